// Round 8
// baseline (2046.533 us; speedup 1.0000x reference)
//
#include <hip/hip_runtime.h>
#include <hip/hip_bf16.h>

// SelfMaskedAttention (Transformer-XL rel-pos), B=8 T=512 D=768 H=12 DH=64.
// VERDICT from R0–R7 forensics: inputs FP32, outputs FP32 (d_out = 9,437,184
// floats: out | k_out | v). Earlier rounds wrote bf16 halves -> the constant
// 2.854 error was k_out packed into out's fp32 window.
// This round: all-fp32 pipeline. ws use = 1.6 MB (projh fp32 + biascp fp32).

#define NT 512
#define ND 768
#define NH 12

typedef short short8_t __attribute__((ext_vector_type(8)));
typedef float float4_t __attribute__((ext_vector_type(4)));

__device__ __forceinline__ float b2f(unsigned short u) {
    union { unsigned int i; float f; } x; x.i = ((unsigned int)u) << 16; return x.f;
}
__device__ __forceinline__ unsigned short f2b(float f) {
    union { float f; unsigned int i; } x; x.f = f;
    unsigned int i = x.i;
    i += 0x7fffu + ((i >> 16) & 1u);   // RNE
    return (unsigned short)(i >> 16);
}

// ---------------- VALU GEMM fp32: C = A(MxK) @ B(K x N tile, stride ldb, col off) + bias ----
// MODE 0: k/v scatter -> o1=k_out (B,H,DH,T) f32, o2=v (B,H,T,DH) f32
// MODE 1: proj -> o1 = projh [H][P][DH] f32
template <int MODE>
__global__ __launch_bounds__(256) void gemm_valu(
    const float* __restrict__ A, const float* __restrict__ Bw,
    const float* __restrict__ biasf,
    float* __restrict__ o1, float* __restrict__ o2,
    int N, int K, int ldb, int coff)
{
    __shared__ float As[64][16];   // [m][k] — 64B rows, float4-aligned
    __shared__ float Bs[16][68];   // [k][n]

    const int tid = threadIdx.x;
    const int m0  = blockIdx.y * 64;
    const int n0  = blockIdx.x * 64;
    const int ty  = tid >> 4;
    const int tx  = tid & 15;

    float acc[4][4];
#pragma unroll
    for (int r = 0; r < 4; ++r)
#pragma unroll
        for (int c = 0; c < 4; ++c) acc[r][c] = 0.f;

    const int sar = tid >> 2;            // 0..63
    const int sac = (tid & 3) * 4;       // 0,4,8,12
    const int sbr = tid >> 4;            // 0..15
    const int sbc = (tid & 15) * 4;      // 0..60

    for (int k0 = 0; k0 < K; k0 += 16) {
        __syncthreads();
        {
            float4_t a4 = *(const float4_t*)&A[(size_t)(m0 + sar) * K + k0 + sac];
            *(float4_t*)&As[sar][sac] = a4;
        }
        {
            float4_t b4 = *(const float4_t*)&Bw[(size_t)(k0 + sbr) * ldb + coff + n0 + sbc];
            Bs[sbr][sbc + 0] = b4[0]; Bs[sbr][sbc + 1] = b4[1];
            Bs[sbr][sbc + 2] = b4[2]; Bs[sbr][sbc + 3] = b4[3];
        }
        __syncthreads();
#pragma unroll
        for (int kk = 0; kk < 16; ++kk) {
            float ar[4], bc[4];
#pragma unroll
            for (int r = 0; r < 4; ++r) ar[r] = As[ty * 4 + r][kk];
#pragma unroll
            for (int c = 0; c < 4; ++c) bc[c] = Bs[kk][tx * 4 + c];
#pragma unroll
            for (int r = 0; r < 4; ++r)
#pragma unroll
                for (int c = 0; c < 4; ++c) acc[r][c] += ar[r] * bc[c];
        }
    }

#pragma unroll
    for (int r = 0; r < 4; ++r) {
        const int grow = m0 + ty * 4 + r;
#pragma unroll
        for (int c = 0; c < 4; ++c) {
            const int gfull = coff + n0 + tx * 4 + c;
            const float val = acc[r][c] + biasf[gfull];
            if (MODE == 0) {
                int b = grow >> 9, t = grow & 511;
                int sec = gfull / 768;                 // 1 or 2
                int cc = gfull - sec * 768;
                int h = cc >> 6, d = cc & 63;
                if (sec == 1) o1[((size_t)((b * NH + h) * 64 + d)) * NT + t] = val; // k_out (B,H,DH,T)
                else          o2[((size_t)((b * NH + h) * NT + t)) * 64 + d] = val; // v (B,H,T,DH)
            } else {
                int h = gfull >> 6, d = gfull & 63;
                o1[((size_t)(h * NT + grow)) * 64 + d] = val;                       // projh[h][p][d]
            }
        }
    }
}

// ---------------- bias_cp[h][p] = sum_d (rcb+rpb)[h][d] * projh[h][p][d] ----------------
__global__ __launch_bounds__(256) void biascp_kernel(
    const float* __restrict__ rcb, const float* __restrict__ rpb,
    const float* __restrict__ projh, float* __restrict__ biascp)
{
    __shared__ float cb[64];
    const int h = blockIdx.x;
    const int tid = threadIdx.x;
    if (tid < 64) cb[tid] = rcb[h * 64 + tid] + rpb[h * 64 + tid];
    __syncthreads();
    for (int p = tid; p < NT; p += 256) {
        const float* pr = &projh[((size_t)(h * NT + p)) * 64];
        float s = 0.f;
#pragma unroll 8
        for (int d = 0; d < 64; ++d) s += pr[d] * cb[d];
        biascp[h * NT + p] = s;
    }
}

// ---------------- fused: q on-the-fly + attention + output projection ----------------
// grid (T/16, B), 256 threads. ctx in LDS; out (fp32) written directly.
__global__ __launch_bounds__(256) void fused_attn(
    const float* __restrict__ x, const float* __restrict__ Wqkv, const float* __restrict__ bqkv,
    const float* __restrict__ Wh, const float* __restrict__ bh,
    const float* __restrict__ kout, const float* __restrict__ vout,
    const float* __restrict__ projh, const float* __restrict__ biascp,
    float* __restrict__ out)
{
    __shared__ __align__(16) unsigned char smem_raw[37376];
    float*          qs  = (float*)(smem_raw);                   // [16][68] f32
    unsigned short* kTl = (unsigned short*)(smem_raw + 4352);   // [64][72] bf16 [d][s]
    unsigned short* vsl = (unsigned short*)(smem_raw + 13568);  // [64][72] bf16 [s][d]
    unsigned short* pTl = (unsigned short*)(smem_raw + 22784);  // [64][80] bf16 [d][p]
    float*          es  = (float*)(smem_raw + 33024);           // [16][68] f32
    __shared__ unsigned short ctxbuf[16][768];                  // bf16, channel = d*12+h
    __shared__ float rowsum[16];

    const int tid  = threadIdx.x;
    const int t0   = blockIdx.x * 16;
    const int b    = blockIdx.y;
    const int wv   = tid >> 6;
    const int lane = tid & 63;
    const int nst  = (t0 + 79) >> 6;

    for (int h = 0; h < NH; ++h) {
        __syncthreads();
        // ---- q on the fly: q[b,h,t0+r,d0..3] = x[b,t0+r,:] . Wqkv[:, h*64+d] + bqkv
        {
            const int r  = tid >> 4;
            const int d0 = (tid & 15) * 4;
            const float* xr = &x[((size_t)(b * NT + t0 + r)) * ND];
            const float* wc = &Wqkv[h * 64 + d0];
            float a0 = bqkv[h * 64 + d0 + 0], a1 = bqkv[h * 64 + d0 + 1];
            float a2 = bqkv[h * 64 + d0 + 2], a3 = bqkv[h * 64 + d0 + 3];
            for (int k = 0; k < ND; ++k) {
                const float xv = xr[k];
                float4_t w = *(const float4_t*)&wc[(size_t)k * 2304];
                a0 += xv * w[0]; a1 += xv * w[1]; a2 += xv * w[2]; a3 += xv * w[3];
            }
            qs[r * 68 + d0 + 0] = a0; qs[r * 68 + d0 + 1] = a1;
            qs[r * 68 + d0 + 2] = a2; qs[r * 68 + d0 + 3] = a3;
        }
        float ctxacc[4] = {0.f, 0.f, 0.f, 0.f};
        float esum[4]   = {0.f, 0.f, 0.f, 0.f};
        __syncthreads();

        for (int st = 0; st < nst; ++st) {
            const int s0  = st * 64;
            const int plo = max(0, t0 - s0 - 63);
            const int cnt = t0 + 15 - s0 - plo + 1;   // 16..79
            if (st) __syncthreads();
            {   // stage K (fp32 -> bf16 LDS, [d][s]) and V ([s][d])
                const int dr = tid >> 2;              // 0..63
                const int cg = (tid & 3) * 16;        // 0,16,32,48
                const float* kb = &kout[((size_t)((b * NH + h) * 64 + dr)) * NT + s0 + cg];
#pragma unroll
                for (int q4 = 0; q4 < 4; ++q4) {
                    float4_t kv = *(const float4_t*)&kb[q4 * 4];
                    kTl[dr * 72 + cg + q4 * 4 + 0] = f2b(kv[0]);
                    kTl[dr * 72 + cg + q4 * 4 + 1] = f2b(kv[1]);
                    kTl[dr * 72 + cg + q4 * 4 + 2] = f2b(kv[2]);
                    kTl[dr * 72 + cg + q4 * 4 + 3] = f2b(kv[3]);
                }
                const float* vb = &vout[((size_t)((b * NH + h) * NT + s0 + dr)) * 64 + cg];
#pragma unroll
                for (int q4 = 0; q4 < 4; ++q4) {
                    float4_t vv = *(const float4_t*)&vb[q4 * 4];
                    vsl[dr * 72 + cg + q4 * 4 + 0] = f2b(vv[0]);
                    vsl[dr * 72 + cg + q4 * 4 + 1] = f2b(vv[1]);
                    vsl[dr * 72 + cg + q4 * 4 + 2] = f2b(vv[2]);
                    vsl[dr * 72 + cg + q4 * 4 + 3] = f2b(vv[3]);
                }
                // proj window transposed [d][p_local]
                const int dc4 = (tid & 15) * 4;
                for (int pr = tid >> 4; pr < cnt; pr += 16) {
                    float4_t pv = *(const float4_t*)&projh[((size_t)(h * NT + plo + pr)) * 64 + dc4];
                    pTl[(dc4 + 0) * 80 + pr] = f2b(pv[0]); pTl[(dc4 + 1) * 80 + pr] = f2b(pv[1]);
                    pTl[(dc4 + 2) * 80 + pr] = f2b(pv[2]); pTl[(dc4 + 3) * 80 + pr] = f2b(pv[3]);
                }
            }
            __syncthreads();
            {   // scores: thread = (s = lane; rows t0 + wv + 4i)
                const int s_g = s0 + lane;
                float sc[4] = {0.f, 0.f, 0.f, 0.f};
                int pl[4]; bool act[4];
#pragma unroll
                for (int i = 0; i < 4; ++i) {
                    const int t_g = t0 + wv + 4 * i;
                    act[i] = (s_g <= t_g);
                    pl[i]  = min(max(t_g - s_g - plo, 0), cnt - 1);
                }
                for (int d = 0; d < 64; ++d) {
                    const float kv = b2f(kTl[d * 72 + lane]);
#pragma unroll
                    for (int i = 0; i < 4; ++i)
                        sc[i] += qs[(wv + 4 * i) * 68 + d] * (kv + b2f(pTl[d * 80 + pl[i]]));
                }
#pragma unroll
                for (int i = 0; i < 4; ++i) {
                    const int tl = wv + 4 * i;
                    const int t_g = t0 + tl;
                    float e = 0.f;
                    if (act[i])
                        e = __expf(fminf((sc[i] + biascp[h * NT + (t_g - s_g)]) * (1.f / 9.f), 60.f));
                    es[tl * 68 + lane] = e;
                    esum[i] += e;
                }
            }
            __syncthreads();
            // ctx accumulate: thread = (d = lane; rows wv + 4i)
            for (int ss = 0; ss < 64; ++ss) {
                const float vv = b2f(vsl[ss * 72 + lane]);
#pragma unroll
                for (int i = 0; i < 4; ++i)
                    ctxacc[i] += es[(wv + 4 * i) * 68 + ss] * vv;
            }
        }
#pragma unroll
        for (int i = 0; i < 4; ++i) {
            float v = esum[i];
#pragma unroll
            for (int off = 32; off > 0; off >>= 1) v += __shfl_xor(v, off);
            if (lane == 0) rowsum[wv + 4 * i] = v;
        }
        __syncthreads();
#pragma unroll
        for (int i = 0; i < 4; ++i) {
            const int tl = wv + 4 * i;
            ctxbuf[tl][lane * NH + h] = f2b(ctxacc[i] / (rowsum[tl] + 2.f));
        }
    }
    __syncthreads();

    // ---- output projection: out[t0+r][n] = ctx[r][:] . Wh[:,n] + bh[n]  (fp32 out)
    {
        float* whl = (float*)smem_raw;        // overlay: [8][768] f32 = 24576 B
        const int r  = tid >> 4;
        const int nb = tid & 15;
        float oacc[48];
#pragma unroll
        for (int j = 0; j < 48; ++j) oacc[j] = bh[nb + 16 * j];
        for (int c0 = 0; c0 < ND; c0 += 8) {
            __syncthreads();
#pragma unroll
            for (int row = 0; row < 8; ++row)
                for (int cc = tid; cc < ND; cc += 256)
                    whl[row * ND + cc] = Wh[(size_t)(c0 + row) * ND + cc];
            __syncthreads();
#pragma unroll
            for (int kk = 0; kk < 8; ++kk) {
                const float cv = b2f(ctxbuf[r][c0 + kk]);
#pragma unroll
                for (int j = 0; j < 48; ++j)
                    oacc[j] += cv * whl[kk * ND + nb + 16 * j];
            }
        }
#pragma unroll
        for (int j = 0; j < 48; ++j)
            out[((size_t)(b * NT + t0 + r)) * ND + nb + 16 * j] = oacc[j];
    }
}

extern "C" void kernel_launch(void* const* d_in, const int* in_sizes, int n_in,
                              void* d_out, int out_size, void* d_ws, size_t ws_size,
                              hipStream_t stream)
{
    const float* x    = (const float*)d_in[0];
    const float* rpe  = (const float*)d_in[1];
    const float* rcb  = (const float*)d_in[2];
    const float* rpb  = (const float*)d_in[3];
    const float* Wqkv = (const float*)d_in[4];
    const float* bqkv = (const float*)d_in[5];
    const float* Wh   = (const float*)d_in[6];
    const float* bh   = (const float*)d_in[7];
    const float* Wp   = (const float*)d_in[8];
    const float* bp   = (const float*)d_in[9];

    float* out  = (float*)d_out;             // (B,T,D) fp32
    float* kout = out + 3145728;             // (B,H,DH,T) fp32
    float* vout = out + 6291456;             // (B,H,T,DH) fp32

    float* projh  = (float*)d_ws;            // [H][P][DH] f32 (1,572,864 B)
    float* biascp = projh + 393216;          // [H][P] f32 (24,576 B) — ws total 1.6 MB

    // 1) K/V projection (cols 768..2303 of Wqkv): M=4096, N=1536, ldb=2304
    gemm_valu<0><<<dim3(1536 / 64, 4096 / 64), 256, 0, stream>>>(
        x, Wqkv, bqkv, kout, vout, 1536, 768, 2304, 768);
    // 2) position projection: M=512, N=768
    gemm_valu<1><<<dim3(768 / 64, 512 / 64), 256, 0, stream>>>(
        rpe, Wp, bp, projh, nullptr, 768, 768, 768, 0);
    // 3) combined content/position bias
    biascp_kernel<<<dim3(12), 256, 0, stream>>>(rcb, rpb, projh, biascp);
    // 4) fused q + attention + out-projection (fp32 out)
    fused_attn<<<dim3(NT / 16, 8), 256, 0, stream>>>(
        x, Wqkv, bqkv, Wh, bh, kout, vout, projh, biascp, out);
}

// Round 9
// 856.518 us; speedup vs baseline: 2.3894x; 2.3894x over previous
//
#include <hip/hip_runtime.h>
#include <hip/hip_bf16.h>

// SelfMaskedAttention (Transformer-XL rel-pos), B=8 T=512 D=768 H=12 DH=64.
// Inputs fp32, outputs fp32 (out | k_out | v). R8 was green at 2046 us with a
// fused kernel at 12% occupancy; this round splits for parallelism:
//  A) qkv VALU GEMM -> q (bf16 ws), k_out/v (fp32 d_out)   [grid 36x64]
//  B) proj VALU GEMM -> projh fp32 ws                      [grid 12x8]
//  C) biascp
//  D) attention per (t-tile, b, h): grid (32, 96), q from ws, K/V from d_out,
//     ctxT bf16 -> ws (channel = d*H + h)
//  E) out-proj VALU GEMM (A = ctxT bf16) -> out fp32       [grid 12x64]
// ws = q 6.3MB + ctxT 6.3MB + projh 1.6MB + biascp 24KB = 14.2 MB.

#define NT 512
#define ND 768
#define NH 12

typedef short short4_t __attribute__((ext_vector_type(4)));
typedef float float4_t __attribute__((ext_vector_type(4)));

__device__ __forceinline__ float b2f(unsigned short u) {
    union { unsigned int i; float f; } x; x.i = ((unsigned int)u) << 16; return x.f;
}
__device__ __forceinline__ unsigned short f2b(float f) {
    union { float f; unsigned int i; } x; x.f = f;
    unsigned int i = x.i;
    i += 0x7fffu + ((i >> 16) & 1u);   // RNE
    return (unsigned short)(i >> 16);
}

// ---------------- VALU GEMM: C = A(MxK) @ B(K x N, stride ldb) + bias ----------------
// MODE 0: qkv -> q bf16 ws (B,H,T,DH), k_out f32 (B,H,DH,T), v f32 (B,H,T,DH)
// MODE 1: proj -> projh [H][P][DH] f32
// MODE 2: out-proj, A = bf16 ctxT -> out f32 row-major
template <int MODE>
__global__ __launch_bounds__(256) void gemm_valu(
    const float* __restrict__ Af, const unsigned short* __restrict__ Ab,
    const float* __restrict__ Bw, const float* __restrict__ biasf,
    unsigned short* __restrict__ ob0, float* __restrict__ o1, float* __restrict__ o2,
    int N, int K, int ldb)
{
    __shared__ float As[64][16];   // [m][k]
    __shared__ float Bs[16][68];   // [k][n]

    const int tid = threadIdx.x;
    const int m0  = blockIdx.y * 64;
    const int n0  = blockIdx.x * 64;
    const int ty  = tid >> 4;
    const int tx  = tid & 15;

    float acc[4][4];
#pragma unroll
    for (int r = 0; r < 4; ++r)
#pragma unroll
        for (int c = 0; c < 4; ++c) acc[r][c] = 0.f;

    const int sar = tid >> 2;            // 0..63
    const int sac = (tid & 3) * 4;       // 0,4,8,12
    const int sbr = tid >> 4;            // 0..15
    const int sbc = (tid & 15) * 4;      // 0..60

    for (int k0 = 0; k0 < K; k0 += 16) {
        __syncthreads();
        if (MODE == 2) {
            union { short4_t v; unsigned short u[4]; } a4;
            a4.v = *(const short4_t*)&Ab[(size_t)(m0 + sar) * K + k0 + sac];
            As[sar][sac + 0] = b2f(a4.u[0]); As[sar][sac + 1] = b2f(a4.u[1]);
            As[sar][sac + 2] = b2f(a4.u[2]); As[sar][sac + 3] = b2f(a4.u[3]);
        } else {
            float4_t a4 = *(const float4_t*)&Af[(size_t)(m0 + sar) * K + k0 + sac];
            *(float4_t*)&As[sar][sac] = a4;
        }
        {
            float4_t b4 = *(const float4_t*)&Bw[(size_t)(k0 + sbr) * ldb + n0 + sbc];
            Bs[sbr][sbc + 0] = b4[0]; Bs[sbr][sbc + 1] = b4[1];
            Bs[sbr][sbc + 2] = b4[2]; Bs[sbr][sbc + 3] = b4[3];
        }
        __syncthreads();
#pragma unroll
        for (int kk = 0; kk < 16; ++kk) {
            float ar[4], bc[4];
#pragma unroll
            for (int r = 0; r < 4; ++r) ar[r] = As[ty * 4 + r][kk];
#pragma unroll
            for (int c = 0; c < 4; ++c) bc[c] = Bs[kk][tx * 4 + c];
#pragma unroll
            for (int r = 0; r < 4; ++r)
#pragma unroll
                for (int c = 0; c < 4; ++c) acc[r][c] += ar[r] * bc[c];
        }
    }

#pragma unroll
    for (int r = 0; r < 4; ++r) {
        const int grow = m0 + ty * 4 + r;
#pragma unroll
        for (int c = 0; c < 4; ++c) {
            const int gcol = n0 + tx * 4 + c;
            const float val = acc[r][c] + biasf[gcol];
            if (MODE == 0) {
                int b = grow >> 9, t = grow & 511;
                int sec = gcol / 768;
                int cc = gcol - sec * 768;
                int h = cc >> 6, d = cc & 63;
                if (sec == 0)      ob0[((size_t)((b * NH + h) * NT + t)) * 64 + d] = f2b(val); // q bf16
                else if (sec == 1) o1[((size_t)((b * NH + h) * 64 + d)) * NT + t] = val;       // k_out
                else               o2[((size_t)((b * NH + h) * NT + t)) * 64 + d] = val;       // v
            } else if (MODE == 1) {
                int h = gcol >> 6, d = gcol & 63;
                o1[((size_t)(h * NT + grow)) * 64 + d] = val;                                  // projh
            } else {
                o1[(size_t)grow * ND + gcol] = val;                                            // out f32
            }
        }
    }
}

// ---------------- bias_cp[h][p] = sum_d (rcb+rpb)[h][d] * projh[h][p][d] ----------------
__global__ __launch_bounds__(256) void biascp_kernel(
    const float* __restrict__ rcb, const float* __restrict__ rpb,
    const float* __restrict__ projh, float* __restrict__ biascp)
{
    __shared__ float cb[64];
    const int h = blockIdx.x;
    const int tid = threadIdx.x;
    if (tid < 64) cb[tid] = rcb[h * 64 + tid] + rpb[h * 64 + tid];
    __syncthreads();
    for (int p = tid; p < NT; p += 256) {
        const float* pr = &projh[((size_t)(h * NT + p)) * 64];
        float s = 0.f;
#pragma unroll 8
        for (int d = 0; d < 64; ++d) s += pr[d] * cb[d];
        biascp[h * NT + p] = s;
    }
}

// ---------------- attention per (t-tile, b*H+h): grid (32, 96), 256 thr ----------------
__global__ __launch_bounds__(256) void attn_kernel(
    const unsigned short* __restrict__ q_ws, const float* __restrict__ kout,
    const float* __restrict__ vout, const float* __restrict__ projh,
    const float* __restrict__ biascp, unsigned short* __restrict__ ctxT)
{
    __shared__ float qs[16][68];            // fp32 q rows
    __shared__ unsigned short kTl[64][72];  // bf16 [d][s]
    __shared__ unsigned short vsl[64][72];  // bf16 [s][d]
    __shared__ unsigned short pTl[64][80];  // bf16 [d][p_local]
    __shared__ float es[16][68];
    __shared__ float rowsum[16];

    const int tid  = threadIdx.x;
    const int y    = blockIdx.y;        // b*H + h
    const int h    = y % NH;
    const int b    = y / NH;
    const int t0   = blockIdx.x * 16;
    const int wv   = tid >> 6;
    const int lane = tid & 63;
    const int nst  = (t0 + 79) >> 6;

    // stage q (bf16 ws -> fp32 LDS)
    {
        const int r   = tid >> 4;
        const int dc4 = (tid & 15) * 4;
        union { short4_t v; unsigned short u[4]; } qv;
        qv.v = *(const short4_t*)&q_ws[((size_t)(y * NT + t0 + r)) * 64 + dc4];
        qs[r][dc4 + 0] = b2f(qv.u[0]); qs[r][dc4 + 1] = b2f(qv.u[1]);
        qs[r][dc4 + 2] = b2f(qv.u[2]); qs[r][dc4 + 3] = b2f(qv.u[3]);
    }
    __syncthreads();

    float ctxacc[4] = {0.f, 0.f, 0.f, 0.f};
    float esum[4]   = {0.f, 0.f, 0.f, 0.f};

    for (int st = 0; st < nst; ++st) {
        const int s0  = st * 64;
        const int plo = max(0, t0 - s0 - 63);
        const int cnt = t0 + 15 - s0 - plo + 1;   // 16..79
        if (st) __syncthreads();
        {   // stage K [d][s], V [s][d], proj [d][p] (fp32 -> bf16)
            const int dr = tid >> 2;              // 0..63
            const int cg = (tid & 3) * 16;        // 0,16,32,48
            const float* kb = &kout[((size_t)((b * NH + h) * 64 + dr)) * NT + s0 + cg];
#pragma unroll
            for (int q4 = 0; q4 < 4; ++q4) {
                float4_t kv = *(const float4_t*)&kb[q4 * 4];
                kTl[dr][cg + q4 * 4 + 0] = f2b(kv[0]); kTl[dr][cg + q4 * 4 + 1] = f2b(kv[1]);
                kTl[dr][cg + q4 * 4 + 2] = f2b(kv[2]); kTl[dr][cg + q4 * 4 + 3] = f2b(kv[3]);
            }
            const float* vb = &vout[((size_t)((b * NH + h) * NT + s0 + dr)) * 64 + cg];
#pragma unroll
            for (int q4 = 0; q4 < 4; ++q4) {
                float4_t vv = *(const float4_t*)&vb[q4 * 4];
                vsl[dr][cg + q4 * 4 + 0] = f2b(vv[0]); vsl[dr][cg + q4 * 4 + 1] = f2b(vv[1]);
                vsl[dr][cg + q4 * 4 + 2] = f2b(vv[2]); vsl[dr][cg + q4 * 4 + 3] = f2b(vv[3]);
            }
            const int dc4 = (tid & 15) * 4;
            for (int pr = tid >> 4; pr < cnt; pr += 16) {
                float4_t pv = *(const float4_t*)&projh[((size_t)(h * NT + plo + pr)) * 64 + dc4];
                pTl[dc4 + 0][pr] = f2b(pv[0]); pTl[dc4 + 1][pr] = f2b(pv[1]);
                pTl[dc4 + 2][pr] = f2b(pv[2]); pTl[dc4 + 3][pr] = f2b(pv[3]);
            }
        }
        __syncthreads();
        {   // scores: thread = (s = lane; rows t0 + wv + 4i)
            const int s_g = s0 + lane;
            float sc[4] = {0.f, 0.f, 0.f, 0.f};
            int pl[4]; bool act[4];
#pragma unroll
            for (int i = 0; i < 4; ++i) {
                const int t_g = t0 + wv + 4 * i;
                act[i] = (s_g <= t_g);
                pl[i]  = min(max(t_g - s_g - plo, 0), cnt - 1);
            }
            for (int d = 0; d < 64; ++d) {
                const float kv = b2f(kTl[d][lane]);
#pragma unroll
                for (int i = 0; i < 4; ++i)
                    sc[i] += qs[wv + 4 * i][d] * (kv + b2f(pTl[d][pl[i]]));
            }
#pragma unroll
            for (int i = 0; i < 4; ++i) {
                const int tl = wv + 4 * i;
                const int t_g = t0 + tl;
                float e = 0.f;
                if (act[i])
                    e = __expf(fminf((sc[i] + biascp[h * NT + (t_g - s_g)]) * (1.f / 9.f), 60.f));
                es[tl][lane] = e;
                esum[i] += e;
            }
        }
        __syncthreads();
        // ctx accumulate: thread = (d = lane; rows wv + 4i)
        for (int ss = 0; ss < 64; ++ss) {
            const float vv = b2f(vsl[ss][lane]);
#pragma unroll
            for (int i = 0; i < 4; ++i)
                ctxacc[i] += es[wv + 4 * i][ss] * vv;
        }
    }

#pragma unroll
    for (int i = 0; i < 4; ++i) {
        float v = esum[i];
#pragma unroll
        for (int off = 32; off > 0; off >>= 1) v += __shfl_xor(v, off);
        if (lane == 0) rowsum[wv + 4 * i] = v;
    }
    __syncthreads();

#pragma unroll
    for (int i = 0; i < 4; ++i) {
        const int tl = wv + 4 * i;
        ctxT[((size_t)(b * NT + t0 + tl)) * ND + lane * NH + h] =
            f2b(ctxacc[i] / (rowsum[tl] + 2.f));
    }
}

extern "C" void kernel_launch(void* const* d_in, const int* in_sizes, int n_in,
                              void* d_out, int out_size, void* d_ws, size_t ws_size,
                              hipStream_t stream)
{
    const float* x    = (const float*)d_in[0];
    const float* rpe  = (const float*)d_in[1];
    const float* rcb  = (const float*)d_in[2];
    const float* rpb  = (const float*)d_in[3];
    const float* Wqkv = (const float*)d_in[4];
    const float* bqkv = (const float*)d_in[5];
    const float* Wh   = (const float*)d_in[6];
    const float* bh   = (const float*)d_in[7];
    const float* Wp   = (const float*)d_in[8];
    const float* bp   = (const float*)d_in[9];

    float* out  = (float*)d_out;             // (B,T,D) fp32
    float* kout = out + 3145728;             // (B,H,DH,T) fp32
    float* vout = out + 6291456;             // (B,H,T,DH) fp32

    unsigned short* q_ws = (unsigned short*)d_ws;        // (B,H,T,DH) bf16, 6.29 MB
    unsigned short* ctxT = q_ws + 3145728;               // (B,T,D) bf16, 6.29 MB
    float* projh  = (float*)(ctxT + 3145728);            // [H][P][DH] f32, 1.57 MB
    float* biascp = projh + 393216;                      // [H][P] f32, 24 KB

    // A) qkv projection: M=4096, N=2304
    gemm_valu<0><<<dim3(2304 / 64, 4096 / 64), 256, 0, stream>>>(
        x, nullptr, Wqkv, bqkv, q_ws, kout, vout, 2304, 768, 2304);
    // B) position projection: M=512, N=768
    gemm_valu<1><<<dim3(768 / 64, 512 / 64), 256, 0, stream>>>(
        rpe, nullptr, Wp, bp, nullptr, projh, nullptr, 768, 768, 768);
    // C) combined content/position bias
    biascp_kernel<<<dim3(12), 256, 0, stream>>>(rcb, rpb, projh, biascp);
    // D) attention -> ctxT
    attn_kernel<<<dim3(NT / 16, 8 * NH), 256, 0, stream>>>(
        q_ws, kout, vout, projh, biascp, ctxT);
    // E) output projection: M=4096, N=768 (A = ctxT bf16)
    gemm_valu<2><<<dim3(768 / 64, 4096 / 64), 256, 0, stream>>>(
        nullptr, ctxT, Wh, bh, nullptr, out, nullptr, 768, 768, 768);
}

// Round 10
// 688.286 us; speedup vs baseline: 2.9734x; 1.2444x over previous
//
#include <hip/hip_runtime.h>
#include <hip/hip_bf16.h>

// SelfMaskedAttention (Transformer-XL rel-pos), B=8 T=512 D=768 H=12 DH=64.
// Inputs fp32, outputs fp32 (out | k_out | v). R9 green @857us (VALU GEMMs 377us,
// attn 479us). This round: GEMMs -> MFMA bf16 (16x16x32), attn UNCHANGED.
// Also validates MFMA A/B/C fragment layouts for next round's attention rewrite.

#define NT 512
#define ND 768
#define NH 12

typedef short short4_t __attribute__((ext_vector_type(4)));
typedef short short8_t __attribute__((ext_vector_type(8)));
typedef float float4_t __attribute__((ext_vector_type(4)));

__device__ __forceinline__ float b2f(unsigned short u) {
    union { unsigned int i; float f; } x; x.i = ((unsigned int)u) << 16; return x.f;
}
__device__ __forceinline__ unsigned short f2b(float f) {
    union { float f; unsigned int i; } x; x.f = f;
    unsigned int i = x.i;
    i += 0x7fffu + ((i >> 16) & 1u);   // RNE
    return (unsigned short)(i >> 16);
}

// ---------------- MFMA GEMM: C = A(MxK) @ B(K x N, stride ldb) + bias ----------------
// A converted to bf16 in staging. 64x64 tile, 4 waves, wave w = rows w*16..w*16+15.
// MODE 0: qkv -> q bf16 ws (B,H,T,DH), k_out f32 (B,H,DH,T), v f32 (B,H,T,DH)
// MODE 1: proj -> projh [H][P][DH] f32
// MODE 2: out-proj, A = bf16 ctxT -> out f32 row-major
template <int MODE>
__global__ __launch_bounds__(256) void gemm_mfma(
    const float* __restrict__ Af, const unsigned short* __restrict__ Ab,
    const float* __restrict__ Bw, const float* __restrict__ biasf,
    unsigned short* __restrict__ ob0, float* __restrict__ o1, float* __restrict__ o2,
    int N, int K, int ldb)
{
    __shared__ unsigned short Al[64][40];  // [m][k] bf16, 80B rows (16B-aligned)
    __shared__ unsigned short Bl[64][40];  // [n][k] bf16 (B transposed)

    const int tid  = threadIdx.x;
    const int m0   = blockIdx.y * 64;
    const int n0   = blockIdx.x * 64;
    const int wave = tid >> 6;
    const int lane = tid & 63;
    const int lm   = lane & 15;
    const int quad = lane >> 4;
    const int koff = quad * 8;

    float4_t acc[4];
#pragma unroll
    for (int j = 0; j < 4; ++j)
#pragma unroll
        for (int r = 0; r < 4; ++r) acc[j][r] = 0.0f;

    const int arow = tid >> 2;        // 0..63
    const int acg  = (tid & 3) * 8;   // 0,8,16,24
    const int bk   = tid & 31;        // 0..31
    const int bg   = tid >> 5;        // 0..7

    for (int k0 = 0; k0 < K; k0 += 32) {
        // stage A (64x32) as bf16
        if (MODE == 2) {
            short8_t av = *(const short8_t*)&Ab[(size_t)(m0 + arow) * K + k0 + acg];
            *(short8_t*)&Al[arow][acg] = av;
        } else {
            const float* src = &Af[(size_t)(m0 + arow) * K + k0 + acg];
            float4_t f0 = *(const float4_t*)src;
            float4_t f1 = *(const float4_t*)(src + 4);
            union { short8_t v; unsigned short u[8]; } pk;
            pk.u[0] = f2b(f0[0]); pk.u[1] = f2b(f0[1]); pk.u[2] = f2b(f0[2]); pk.u[3] = f2b(f0[3]);
            pk.u[4] = f2b(f1[0]); pk.u[5] = f2b(f1[1]); pk.u[6] = f2b(f1[2]); pk.u[7] = f2b(f1[3]);
            *(short8_t*)&Al[arow][acg] = pk.v;
        }
        // stage B transposed: Bl[n][k] = bf16(B[k0+k][n0+n])
        {
            const float* src = &Bw[(size_t)(k0 + bk) * ldb + n0 + bg * 8];
            float4_t f0 = *(const float4_t*)src;
            float4_t f1 = *(const float4_t*)(src + 4);
            Bl[bg * 8 + 0][bk] = f2b(f0[0]); Bl[bg * 8 + 1][bk] = f2b(f0[1]);
            Bl[bg * 8 + 2][bk] = f2b(f0[2]); Bl[bg * 8 + 3][bk] = f2b(f0[3]);
            Bl[bg * 8 + 4][bk] = f2b(f1[0]); Bl[bg * 8 + 5][bk] = f2b(f1[1]);
            Bl[bg * 8 + 6][bk] = f2b(f1[2]); Bl[bg * 8 + 7][bk] = f2b(f1[3]);
        }
        __syncthreads();

        short8_t af = *(const short8_t*)&Al[wave * 16 + lm][koff];
#pragma unroll
        for (int j = 0; j < 4; ++j) {
            short8_t bf = *(const short8_t*)&Bl[j * 16 + lm][koff];
            acc[j] = __builtin_amdgcn_mfma_f32_16x16x32_bf16(af, bf, acc[j], 0, 0, 0);
        }
        __syncthreads();
    }

#pragma unroll
    for (int j = 0; j < 4; ++j) {
        const int gcol = n0 + j * 16 + lm;
        const float bv = biasf[gcol];
#pragma unroll
        for (int r = 0; r < 4; ++r) {
            const int grow = m0 + wave * 16 + quad * 4 + r;
            const float val = acc[j][r] + bv;
            if (MODE == 0) {
                int b = grow >> 9, t = grow & 511;
                int sec = gcol / 768;
                int cc = gcol - sec * 768;
                int h = cc >> 6, d = cc & 63;
                if (sec == 0)      ob0[((size_t)((b * NH + h) * NT + t)) * 64 + d] = f2b(val); // q bf16
                else if (sec == 1) o1[((size_t)((b * NH + h) * 64 + d)) * NT + t] = val;       // k_out
                else               o2[((size_t)((b * NH + h) * NT + t)) * 64 + d] = val;       // v
            } else if (MODE == 1) {
                int h = gcol >> 6, d = gcol & 63;
                o1[((size_t)(h * NT + grow)) * 64 + d] = val;                                  // projh
            } else {
                o1[(size_t)grow * ND + gcol] = val;                                            // out f32
            }
        }
    }
}

// ---------------- bias_cp[h][p] = sum_d (rcb+rpb)[h][d] * projh[h][p][d] ----------------
__global__ __launch_bounds__(256) void biascp_kernel(
    const float* __restrict__ rcb, const float* __restrict__ rpb,
    const float* __restrict__ projh, float* __restrict__ biascp)
{
    __shared__ float cb[64];
    const int h = blockIdx.x;
    const int tid = threadIdx.x;
    if (tid < 64) cb[tid] = rcb[h * 64 + tid] + rpb[h * 64 + tid];
    __syncthreads();
    for (int p = tid; p < NT; p += 256) {
        const float* pr = &projh[((size_t)(h * NT + p)) * 64];
        float s = 0.f;
#pragma unroll 8
        for (int d = 0; d < 64; ++d) s += pr[d] * cb[d];
        biascp[h * NT + p] = s;
    }
}

// ---------------- attention per (t-tile, b*H+h): grid (32, 96), 256 thr ----------------
// UNCHANGED from R9 (known-good).
__global__ __launch_bounds__(256) void attn_kernel(
    const unsigned short* __restrict__ q_ws, const float* __restrict__ kout,
    const float* __restrict__ vout, const float* __restrict__ projh,
    const float* __restrict__ biascp, unsigned short* __restrict__ ctxT)
{
    __shared__ float qs[16][68];
    __shared__ unsigned short kTl[64][72];
    __shared__ unsigned short vsl[64][72];
    __shared__ unsigned short pTl[64][80];
    __shared__ float es[16][68];
    __shared__ float rowsum[16];

    const int tid  = threadIdx.x;
    const int y    = blockIdx.y;        // b*H + h
    const int h    = y % NH;
    const int b    = y / NH;
    const int t0   = blockIdx.x * 16;
    const int wv   = tid >> 6;
    const int lane = tid & 63;
    const int nst  = (t0 + 79) >> 6;

    {
        const int r   = tid >> 4;
        const int dc4 = (tid & 15) * 4;
        union { short4_t v; unsigned short u[4]; } qv;
        qv.v = *(const short4_t*)&q_ws[((size_t)(y * NT + t0 + r)) * 64 + dc4];
        qs[r][dc4 + 0] = b2f(qv.u[0]); qs[r][dc4 + 1] = b2f(qv.u[1]);
        qs[r][dc4 + 2] = b2f(qv.u[2]); qs[r][dc4 + 3] = b2f(qv.u[3]);
    }
    __syncthreads();

    float ctxacc[4] = {0.f, 0.f, 0.f, 0.f};
    float esum[4]   = {0.f, 0.f, 0.f, 0.f};

    for (int st = 0; st < nst; ++st) {
        const int s0  = st * 64;
        const int plo = max(0, t0 - s0 - 63);
        const int cnt = t0 + 15 - s0 - plo + 1;
        if (st) __syncthreads();
        {
            const int dr = tid >> 2;
            const int cg = (tid & 3) * 16;
            const float* kb = &kout[((size_t)((b * NH + h) * 64 + dr)) * NT + s0 + cg];
#pragma unroll
            for (int q4 = 0; q4 < 4; ++q4) {
                float4_t kv = *(const float4_t*)&kb[q4 * 4];
                kTl[dr][cg + q4 * 4 + 0] = f2b(kv[0]); kTl[dr][cg + q4 * 4 + 1] = f2b(kv[1]);
                kTl[dr][cg + q4 * 4 + 2] = f2b(kv[2]); kTl[dr][cg + q4 * 4 + 3] = f2b(kv[3]);
            }
            const float* vb = &vout[((size_t)((b * NH + h) * NT + s0 + dr)) * 64 + cg];
#pragma unroll
            for (int q4 = 0; q4 < 4; ++q4) {
                float4_t vv = *(const float4_t*)&vb[q4 * 4];
                vsl[dr][cg + q4 * 4 + 0] = f2b(vv[0]); vsl[dr][cg + q4 * 4 + 1] = f2b(vv[1]);
                vsl[dr][cg + q4 * 4 + 2] = f2b(vv[2]); vsl[dr][cg + q4 * 4 + 3] = f2b(vv[3]);
            }
            const int dc4 = (tid & 15) * 4;
            for (int pr = tid >> 4; pr < cnt; pr += 16) {
                float4_t pv = *(const float4_t*)&projh[((size_t)(h * NT + plo + pr)) * 64 + dc4];
                pTl[dc4 + 0][pr] = f2b(pv[0]); pTl[dc4 + 1][pr] = f2b(pv[1]);
                pTl[dc4 + 2][pr] = f2b(pv[2]); pTl[dc4 + 3][pr] = f2b(pv[3]);
            }
        }
        __syncthreads();
        {
            const int s_g = s0 + lane;
            float sc[4] = {0.f, 0.f, 0.f, 0.f};
            int pl[4]; bool act[4];
#pragma unroll
            for (int i = 0; i < 4; ++i) {
                const int t_g = t0 + wv + 4 * i;
                act[i] = (s_g <= t_g);
                pl[i]  = min(max(t_g - s_g - plo, 0), cnt - 1);
            }
            for (int d = 0; d < 64; ++d) {
                const float kv = b2f(kTl[d][lane]);
#pragma unroll
                for (int i = 0; i < 4; ++i)
                    sc[i] += qs[wv + 4 * i][d] * (kv + b2f(pTl[d][pl[i]]));
            }
#pragma unroll
            for (int i = 0; i < 4; ++i) {
                const int tl = wv + 4 * i;
                const int t_g = t0 + tl;
                float e = 0.f;
                if (act[i])
                    e = __expf(fminf((sc[i] + biascp[h * NT + (t_g - s_g)]) * (1.f / 9.f), 60.f));
                es[tl][lane] = e;
                esum[i] += e;
            }
        }
        __syncthreads();
        for (int ss = 0; ss < 64; ++ss) {
            const float vv = b2f(vsl[ss][lane]);
#pragma unroll
            for (int i = 0; i < 4; ++i)
                ctxacc[i] += es[wv + 4 * i][ss] * vv;
        }
    }

#pragma unroll
    for (int i = 0; i < 4; ++i) {
        float v = esum[i];
#pragma unroll
        for (int off = 32; off > 0; off >>= 1) v += __shfl_xor(v, off);
        if (lane == 0) rowsum[wv + 4 * i] = v;
    }
    __syncthreads();

#pragma unroll
    for (int i = 0; i < 4; ++i) {
        const int tl = wv + 4 * i;
        ctxT[((size_t)(b * NT + t0 + tl)) * ND + lane * NH + h] =
            f2b(ctxacc[i] / (rowsum[tl] + 2.f));
    }
}

extern "C" void kernel_launch(void* const* d_in, const int* in_sizes, int n_in,
                              void* d_out, int out_size, void* d_ws, size_t ws_size,
                              hipStream_t stream)
{
    const float* x    = (const float*)d_in[0];
    const float* rpe  = (const float*)d_in[1];
    const float* rcb  = (const float*)d_in[2];
    const float* rpb  = (const float*)d_in[3];
    const float* Wqkv = (const float*)d_in[4];
    const float* bqkv = (const float*)d_in[5];
    const float* Wh   = (const float*)d_in[6];
    const float* bh   = (const float*)d_in[7];
    const float* Wp   = (const float*)d_in[8];
    const float* bp   = (const float*)d_in[9];

    float* out  = (float*)d_out;             // (B,T,D) fp32
    float* kout = out + 3145728;             // (B,H,DH,T) fp32
    float* vout = out + 6291456;             // (B,H,T,DH) fp32

    unsigned short* q_ws = (unsigned short*)d_ws;        // (B,H,T,DH) bf16
    unsigned short* ctxT = q_ws + 3145728;               // (B,T,D) bf16
    float* projh  = (float*)(ctxT + 3145728);            // [H][P][DH] f32
    float* biascp = projh + 393216;                      // [H][P] f32 — ws total 14.2 MB

    // A) qkv projection: M=4096, N=2304 (MFMA)
    gemm_mfma<0><<<dim3(2304 / 64, 4096 / 64), 256, 0, stream>>>(
        x, nullptr, Wqkv, bqkv, q_ws, kout, vout, 2304, 768, 2304);
    // B) position projection: M=512, N=768 (MFMA)
    gemm_mfma<1><<<dim3(768 / 64, 512 / 64), 256, 0, stream>>>(
        rpe, nullptr, Wp, bp, nullptr, projh, nullptr, 768, 768, 768);
    // C) combined content/position bias
    biascp_kernel<<<dim3(12), 256, 0, stream>>>(rcb, rpb, projh, biascp);
    // D) attention -> ctxT (unchanged)
    attn_kernel<<<dim3(NT / 16, 8 * NH), 256, 0, stream>>>(
        q_ws, kout, vout, projh, biascp, ctxT);
    // E) output projection: M=4096, N=768 (MFMA, A = ctxT bf16)
    gemm_mfma<2><<<dim3(768 / 64, 4096 / 64), 256, 0, stream>>>(
        nullptr, ctxT, Wh, bh, nullptr, out, nullptr, 768, 768, 768);
}

// Round 11
// 406.108 us; speedup vs baseline: 5.0394x; 1.6948x over previous
//
#include <hip/hip_runtime.h>
#include <hip/hip_bf16.h>

// SelfMaskedAttention (Transformer-XL rel-pos), B=8 T=512 D=768 H=12 DH=64.
// Inputs fp32, outputs fp32 (out | k_out | v). R10 green @688us, attn 488us
// VALU-bound. This round: attention -> MFMA (QK^T, R=Q.proj^T w/ bias folded,
// P.V), using fragment layouts validated by the R10 GEMMs. GEMMs unchanged.

#define NT 512
#define ND 768
#define NH 12

typedef short short4_t __attribute__((ext_vector_type(4)));
typedef short short8_t __attribute__((ext_vector_type(8)));
typedef float float4_t __attribute__((ext_vector_type(4)));

__device__ __forceinline__ float b2f(unsigned short u) {
    union { unsigned int i; float f; } x; x.i = ((unsigned int)u) << 16; return x.f;
}
__device__ __forceinline__ unsigned short f2b(float f) {
    union { float f; unsigned int i; } x; x.f = f;
    unsigned int i = x.i;
    i += 0x7fffu + ((i >> 16) & 1u);   // RNE
    return (unsigned short)(i >> 16);
}

// ---------------- MFMA GEMM (unchanged from R10) ----------------
template <int MODE>
__global__ __launch_bounds__(256) void gemm_mfma(
    const float* __restrict__ Af, const unsigned short* __restrict__ Ab,
    const float* __restrict__ Bw, const float* __restrict__ biasf,
    unsigned short* __restrict__ ob0, float* __restrict__ o1, float* __restrict__ o2,
    int N, int K, int ldb)
{
    __shared__ unsigned short Al[64][40];
    __shared__ unsigned short Bl[64][40];

    const int tid  = threadIdx.x;
    const int m0   = blockIdx.y * 64;
    const int n0   = blockIdx.x * 64;
    const int wave = tid >> 6;
    const int lane = tid & 63;
    const int lm   = lane & 15;
    const int quad = lane >> 4;
    const int koff = quad * 8;

    float4_t acc[4];
#pragma unroll
    for (int j = 0; j < 4; ++j)
#pragma unroll
        for (int r = 0; r < 4; ++r) acc[j][r] = 0.0f;

    const int arow = tid >> 2;
    const int acg  = (tid & 3) * 8;
    const int bk   = tid & 31;
    const int bg   = tid >> 5;

    for (int k0 = 0; k0 < K; k0 += 32) {
        if (MODE == 2) {
            short8_t av = *(const short8_t*)&Ab[(size_t)(m0 + arow) * K + k0 + acg];
            *(short8_t*)&Al[arow][acg] = av;
        } else {
            const float* src = &Af[(size_t)(m0 + arow) * K + k0 + acg];
            float4_t f0 = *(const float4_t*)src;
            float4_t f1 = *(const float4_t*)(src + 4);
            union { short8_t v; unsigned short u[8]; } pk;
            pk.u[0] = f2b(f0[0]); pk.u[1] = f2b(f0[1]); pk.u[2] = f2b(f0[2]); pk.u[3] = f2b(f0[3]);
            pk.u[4] = f2b(f1[0]); pk.u[5] = f2b(f1[1]); pk.u[6] = f2b(f1[2]); pk.u[7] = f2b(f1[3]);
            *(short8_t*)&Al[arow][acg] = pk.v;
        }
        {
            const float* src = &Bw[(size_t)(k0 + bk) * ldb + n0 + bg * 8];
            float4_t f0 = *(const float4_t*)src;
            float4_t f1 = *(const float4_t*)(src + 4);
            Bl[bg * 8 + 0][bk] = f2b(f0[0]); Bl[bg * 8 + 1][bk] = f2b(f0[1]);
            Bl[bg * 8 + 2][bk] = f2b(f0[2]); Bl[bg * 8 + 3][bk] = f2b(f0[3]);
            Bl[bg * 8 + 4][bk] = f2b(f1[0]); Bl[bg * 8 + 5][bk] = f2b(f1[1]);
            Bl[bg * 8 + 6][bk] = f2b(f1[2]); Bl[bg * 8 + 7][bk] = f2b(f1[3]);
        }
        __syncthreads();

        short8_t af = *(const short8_t*)&Al[wave * 16 + lm][koff];
#pragma unroll
        for (int j = 0; j < 4; ++j) {
            short8_t bf = *(const short8_t*)&Bl[j * 16 + lm][koff];
            acc[j] = __builtin_amdgcn_mfma_f32_16x16x32_bf16(af, bf, acc[j], 0, 0, 0);
        }
        __syncthreads();
    }

#pragma unroll
    for (int j = 0; j < 4; ++j) {
        const int gcol = n0 + j * 16 + lm;
        const float bv = biasf[gcol];
#pragma unroll
        for (int r = 0; r < 4; ++r) {
            const int grow = m0 + wave * 16 + quad * 4 + r;
            const float val = acc[j][r] + bv;
            if (MODE == 0) {
                int b = grow >> 9, t = grow & 511;
                int sec = gcol / 768;
                int cc = gcol - sec * 768;
                int h = cc >> 6, d = cc & 63;
                if (sec == 0)      ob0[((size_t)((b * NH + h) * NT + t)) * 64 + d] = f2b(val);
                else if (sec == 1) o1[((size_t)((b * NH + h) * 64 + d)) * NT + t] = val;
                else               o2[((size_t)((b * NH + h) * NT + t)) * 64 + d] = val;
            } else if (MODE == 1) {
                int h = gcol >> 6, d = gcol & 63;
                o1[((size_t)(h * NT + grow)) * 64 + d] = val;
            } else {
                o1[(size_t)grow * ND + gcol] = val;
            }
        }
    }
}

// ---------------- bias_cp (unchanged) ----------------
__global__ __launch_bounds__(256) void biascp_kernel(
    const float* __restrict__ rcb, const float* __restrict__ rpb,
    const float* __restrict__ projh, float* __restrict__ biascp)
{
    __shared__ float cb[64];
    const int h = blockIdx.x;
    const int tid = threadIdx.x;
    if (tid < 64) cb[tid] = rcb[h * 64 + tid] + rpb[h * 64 + tid];
    __syncthreads();
    for (int p = tid; p < NT; p += 256) {
        const float* pr = &projh[((size_t)(h * NT + p)) * 64];
        float s = 0.f;
#pragma unroll 8
        for (int d = 0; d < 64; ++d) s += pr[d] * cb[d];
        biascp[h * NT + p] = s;
    }
}

// ---------------- MFMA attention: grid (32, 96), 256 thr ----------------
// Per s-tile: QK^T (<=8 mfma) + R = Q.proj^T (<=10 mfma, bias folded at Rl
// write since gather index t-s == R column) + e = exp(.)*mask + P.V (8 mfma).
__global__ __launch_bounds__(256) void attn_mfma(
    const unsigned short* __restrict__ q_ws, const float* __restrict__ kout,
    const float* __restrict__ vout, const float* __restrict__ projh,
    const float* __restrict__ biascp, unsigned short* __restrict__ ctxT)
{
    __shared__ unsigned short Qs[16][72];   // [t][d] bf16 (rows 144B, 16B-aligned)
    __shared__ unsigned short Kt[64][72];   // [s][d] bf16 (transposed from kout [d][t])
    __shared__ unsigned short Vt[64][72];   // [d][s] bf16 (transposed from vout [s][d])
    __shared__ unsigned short pP[80][72];   // [p][d] bf16 (rel-window, zero-padded)
    __shared__ float          Rl[16][84];   // R + bias, f32
    __shared__ unsigned short esl[16][72];  // e bf16 (PV A-operand)

    const int tid  = threadIdx.x;
    const int y    = blockIdx.y;        // b*H + h
    const int h    = y % NH;
    const int b    = y / NH;
    const int t0   = blockIdx.x * 16;
    const int lane = tid & 63;
    const int lm   = lane & 15;
    const int quad = lane >> 4;
    const int koff = quad * 8;
    const int nst  = (t0 + 79) >> 6;

    // stage Q once (bf16 ws [t][d] -> straight copy)
    {
        const int r   = tid >> 4;
        const int dc4 = (tid & 15) * 4;
        *(short4_t*)&Qs[r][dc4] = *(const short4_t*)&q_ws[((size_t)(y * NT + t0 + r)) * 64 + dc4];
    }
    __syncthreads();

    short8_t aq[2];
    aq[0] = *(const short8_t*)&Qs[lm][koff];
    aq[1] = *(const short8_t*)&Qs[lm][koff + 32];

    float4_t ctxacc[4];
#pragma unroll
    for (int j = 0; j < 4; ++j)
#pragma unroll
        for (int r = 0; r < 4; ++r) ctxacc[j][r] = 0.f;
    float esum[4] = {0.f, 0.f, 0.f, 0.f};

    for (int st = 0; st < nst; ++st) {
        const int s0    = st * 64;
        const int plo   = max(0, t0 - s0 - 63);
        const int cnt   = t0 + 15 - s0 - plo + 1;        // 16..79
        const int jmax  = min(3, (t0 + 15 - s0) >> 4);   // QK n-tiles with any active s
        const int jpmax = min(4, (cnt - 1) >> 4);        // R n-tiles
        if (st) __syncthreads();
        {   // ---- stage K^T, V^T, proj window
            const int g4 = tid >> 2;           // 0..63
            const int c16 = (tid & 3) * 16;    // 0,16,32,48
            // K: read kout row d=g4 (16 consecutive t), scatter to Kt[s][d]
            const float* kb = &kout[((size_t)(y * 64 + g4)) * NT + s0 + c16];
#pragma unroll
            for (int q4 = 0; q4 < 4; ++q4) {
                float4_t kv = *(const float4_t*)&kb[q4 * 4];
                Kt[c16 + q4 * 4 + 0][g4] = f2b(kv[0]); Kt[c16 + q4 * 4 + 1][g4] = f2b(kv[1]);
                Kt[c16 + q4 * 4 + 2][g4] = f2b(kv[2]); Kt[c16 + q4 * 4 + 3][g4] = f2b(kv[3]);
            }
            // V: read vout row s=g4 (16 consecutive d), scatter to Vt[d][s]
            const float* vb = &vout[((size_t)(y * NT + s0 + g4)) * 64 + c16];
#pragma unroll
            for (int q4 = 0; q4 < 4; ++q4) {
                float4_t vv = *(const float4_t*)&vb[q4 * 4];
                Vt[c16 + q4 * 4 + 0][g4] = f2b(vv[0]); Vt[c16 + q4 * 4 + 1][g4] = f2b(vv[1]);
                Vt[c16 + q4 * 4 + 2][g4] = f2b(vv[2]); Vt[c16 + q4 * 4 + 3][g4] = f2b(vv[3]);
            }
            // proj window [p][d] (straight rows), zero-fill p >= cnt
            const int pr0 = tid >> 4;
            const int dc4 = (tid & 15) * 4;
            for (int pr = pr0; pr < 80; pr += 16) {
                if (pr < cnt) {
                    float4_t pv = *(const float4_t*)&projh[((size_t)(h * NT + plo + pr)) * 64 + dc4];
                    pP[pr][dc4 + 0] = f2b(pv[0]); pP[pr][dc4 + 1] = f2b(pv[1]);
                    pP[pr][dc4 + 2] = f2b(pv[2]); pP[pr][dc4 + 3] = f2b(pv[3]);
                } else {
                    pP[pr][dc4 + 0] = 0; pP[pr][dc4 + 1] = 0;
                    pP[pr][dc4 + 2] = 0; pP[pr][dc4 + 3] = 0;
                }
            }
        }
        __syncthreads();

        // ---- QK^T and R mfma
        float4_t accQK[4];
#pragma unroll
        for (int j = 0; j < 4; ++j)
#pragma unroll
            for (int r = 0; r < 4; ++r) accQK[j][r] = 0.f;
        for (int j = 0; j <= jmax; ++j) {
            short8_t bk0 = *(const short8_t*)&Kt[j * 16 + lm][koff];
            short8_t bk1 = *(const short8_t*)&Kt[j * 16 + lm][koff + 32];
            accQK[j] = __builtin_amdgcn_mfma_f32_16x16x32_bf16(aq[0], bk0, accQK[j], 0, 0, 0);
            accQK[j] = __builtin_amdgcn_mfma_f32_16x16x32_bf16(aq[1], bk1, accQK[j], 0, 0, 0);
        }
        for (int j = 0; j <= jpmax; ++j) {
            short8_t bp0 = *(const short8_t*)&pP[j * 16 + lm][koff];
            short8_t bp1 = *(const short8_t*)&pP[j * 16 + lm][koff + 32];
            float4_t accR;
#pragma unroll
            for (int r = 0; r < 4; ++r) accR[r] = 0.f;
            accR = __builtin_amdgcn_mfma_f32_16x16x32_bf16(aq[0], bp0, accR, 0, 0, 0);
            accR = __builtin_amdgcn_mfma_f32_16x16x32_bf16(aq[1], bp1, accR, 0, 0, 0);
            const int p = j * 16 + lm;
            const float bv = biascp[h * NT + min(plo + p, NT - 1)];
#pragma unroll
            for (int r = 0; r < 4; ++r) Rl[quad * 4 + r][p] = accR[r] + bv;
        }
        __syncthreads();   // Rl visible (cross-lane gather next)

        // ---- e = exp((QK + R[t][t-s-plo]) / 9) * mask; esum in f32 regs
#pragma unroll
        for (int j = 0; j < 4; ++j) {
            const int s_g = s0 + j * 16 + lm;
#pragma unroll
            for (int r = 0; r < 4; ++r) {
                const int t_g = t0 + quad * 4 + r;
                float e = 0.f;
                if (s_g <= t_g) {
                    const int p = t_g - s_g - plo;
                    e = __expf(fminf((accQK[j][r] + Rl[quad * 4 + r][p]) * (1.f / 9.f), 60.f));
                }
                esl[quad * 4 + r][j * 16 + lm] = f2b(e);
                esum[r] += e;
            }
        }
        __syncthreads();   // esl visible (cross-quad A-fragment reads next)

        // ---- P.V mfma: ctx[t][d] += e[t][s] * V[s][d]
        short8_t ae0 = *(const short8_t*)&esl[lm][koff];
        short8_t ae1 = *(const short8_t*)&esl[lm][koff + 32];
#pragma unroll
        for (int j = 0; j < 4; ++j) {
            short8_t bv0 = *(const short8_t*)&Vt[j * 16 + lm][koff];
            short8_t bv1 = *(const short8_t*)&Vt[j * 16 + lm][koff + 32];
            ctxacc[j] = __builtin_amdgcn_mfma_f32_16x16x32_bf16(ae0, bv0, ctxacc[j], 0, 0, 0);
            ctxacc[j] = __builtin_amdgcn_mfma_f32_16x16x32_bf16(ae1, bv1, ctxacc[j], 0, 0, 0);
        }
    }

    // row-sum reduce within each quad's 16 lanes (rows owned per quad)
    float rcp[4];
#pragma unroll
    for (int r = 0; r < 4; ++r) {
        float v = esum[r];
        v += __shfl_xor(v, 1); v += __shfl_xor(v, 2);
        v += __shfl_xor(v, 4); v += __shfl_xor(v, 8);
        rcp[r] = 1.f / (v + 2.f);
    }

    // write ctxT: channel = d*H + h, row t (C-layout: row=quad*4+r, col d=j*16+lm)
#pragma unroll
    for (int j = 0; j < 4; ++j) {
        const int d = j * 16 + lm;
#pragma unroll
        for (int r = 0; r < 4; ++r) {
            const int t = t0 + quad * 4 + r;
            ctxT[((size_t)(b * NT + t)) * ND + d * NH + h] = f2b(ctxacc[j][r] * rcp[r]);
        }
    }
}

extern "C" void kernel_launch(void* const* d_in, const int* in_sizes, int n_in,
                              void* d_out, int out_size, void* d_ws, size_t ws_size,
                              hipStream_t stream)
{
    const float* x    = (const float*)d_in[0];
    const float* rpe  = (const float*)d_in[1];
    const float* rcb  = (const float*)d_in[2];
    const float* rpb  = (const float*)d_in[3];
    const float* Wqkv = (const float*)d_in[4];
    const float* bqkv = (const float*)d_in[5];
    const float* Wh   = (const float*)d_in[6];
    const float* bh   = (const float*)d_in[7];
    const float* Wp   = (const float*)d_in[8];
    const float* bp   = (const float*)d_in[9];

    float* out  = (float*)d_out;             // (B,T,D) fp32
    float* kout = out + 3145728;             // (B,H,DH,T) fp32
    float* vout = out + 6291456;             // (B,H,T,DH) fp32

    unsigned short* q_ws = (unsigned short*)d_ws;        // (B,H,T,DH) bf16
    unsigned short* ctxT = q_ws + 3145728;               // (B,T,D) bf16
    float* projh  = (float*)(ctxT + 3145728);            // [H][P][DH] f32
    float* biascp = projh + 393216;                      // [H][P] f32 — ws 14.2 MB

    gemm_mfma<0><<<dim3(2304 / 64, 4096 / 64), 256, 0, stream>>>(
        x, nullptr, Wqkv, bqkv, q_ws, kout, vout, 2304, 768, 2304);
    gemm_mfma<1><<<dim3(768 / 64, 512 / 64), 256, 0, stream>>>(
        rpe, nullptr, Wp, bp, nullptr, projh, nullptr, 768, 768, 768);
    biascp_kernel<<<dim3(12), 256, 0, stream>>>(rcb, rpb, projh, biascp);
    attn_mfma<<<dim3(NT / 16, 8 * NH), 256, 0, stream>>>(
        q_ws, kout, vout, projh, biascp, ctxT);
    gemm_mfma<2><<<dim3(768 / 64, 4096 / 64), 256, 0, stream>>>(
        nullptr, ctxT, Wh, bh, nullptr, out, nullptr, 768, 768, 768);
}